// Round 1
// baseline (1433.352 us; speedup 1.0000x reference)
//
#include <hip/hip_runtime.h>
#include <hip/hip_bf16.h>

#define HIDC 64
#define OUTC 16
#define INC 128

// ---------------- degree / normalization ----------------
__global__ __launch_bounds__(256) void init_deg(float* deg, int n) {
    int i = blockIdx.x * 256 + threadIdx.x;
    if (i < n) deg[i] = 1.0f;  // self-loop contributes 1
}

__global__ __launch_bounds__(256) void count_deg(const int* __restrict__ dst, float* deg, int n_edges) {
    int stride = gridDim.x * 256;
    for (int e = blockIdx.x * 256 + threadIdx.x; e < n_edges; e += stride)
        atomicAdd(&deg[dst[e]], 1.0f);
}

__global__ __launch_bounds__(256) void finish_dis(float* deg, int n) {
    int i = blockIdx.x * 256 + threadIdx.x;
    if (i < n) deg[i] = rsqrtf(deg[i]);  // deg >= 1 always (self loops)
}

// ---------------- GEMM 1: xW = x @ W1   [N,128]x[128,64] ----------------
__global__ __launch_bounds__(256) void gemm_x_w(const float* __restrict__ x,
                                                const float* __restrict__ W,
                                                float* __restrict__ out, int n_nodes) {
    __shared__ float Wl[INC * HIDC];   // 32 KB
    __shared__ float xr[4][INC];       // 2 KB
    for (int i = threadIdx.x; i < INC * HIDC; i += 256) Wl[i] = W[i];
    const int wid = threadIdx.x >> 6, lane = threadIdx.x & 63;
    for (int base = blockIdx.x * 4; base < n_nodes; base += gridDim.x * 4) {
        int nrows = min(4, n_nodes - base);
        __syncthreads();  // protect xr (and Wl on first iter)
        for (int i = threadIdx.x; i < nrows * INC; i += 256)
            xr[i >> 7][i & 127] = x[(size_t)base * INC + i];
        __syncthreads();
        if (wid < nrows) {
            float acc = 0.f;
            #pragma unroll
            for (int k = 0; k < INC; ++k) acc += xr[wid][k] * Wl[k * HIDC + lane];
            out[(size_t)(base + wid) * HIDC + lane] = acc;
        }
    }
}

// ---------------- GEMM 2: hw = h @ [W_mu | W_ls]   [N,64]x[64,32] ----------------
__global__ __launch_bounds__(256) void gemm_h_w(const float* __restrict__ h,
                                                const float* __restrict__ Wmu,
                                                const float* __restrict__ Wls,
                                                float* __restrict__ out, int n_nodes) {
    __shared__ float Wl[HIDC * 32];   // 8 KB
    __shared__ float hr[8][HIDC];     // 2 KB
    for (int i = threadIdx.x; i < HIDC * OUTC; i += 256) {
        int k = i >> 4, c = i & 15;
        Wl[k * 32 + c]      = Wmu[i];
        Wl[k * 32 + 16 + c] = Wls[i];
    }
    const int wid = threadIdx.x >> 6, lane = threadIdx.x & 63;
    const int sub = lane >> 5, ch = lane & 31;
    for (int base = blockIdx.x * 8; base < n_nodes; base += gridDim.x * 8) {
        int nrows = min(8, n_nodes - base);
        __syncthreads();
        for (int i = threadIdx.x; i < nrows * HIDC; i += 256)
            hr[i >> 6][i & 63] = h[(size_t)base * HIDC + i];
        __syncthreads();
        int n = wid * 2 + sub;
        if (n < nrows) {
            float acc = 0.f;
            #pragma unroll
            for (int k = 0; k < HIDC; ++k) acc += hr[n][k] * Wl[k * 32 + ch];
            out[(size_t)(base + n) * 32 + ch] = acc;
        }
    }
}

// ---------------- edge scatter: out[dst] += rows[src] * dis[src]*dis[dst] ----------------
template <int C>
__global__ __launch_bounds__(256) void scatter_edges(const float* __restrict__ rows,
                                                     float* __restrict__ out,
                                                     const int* __restrict__ src,
                                                     const int* __restrict__ dst,
                                                     const float* __restrict__ dis,
                                                     int n_edges) {
    constexpr int EPI = 64 / C;  // edges per inner iteration
    const int lane = threadIdx.x & 63;
    const int ch = lane % C;
    const int sub = lane / C;
    int wave = blockIdx.x * (blockDim.x >> 6) + (threadIdx.x >> 6);
    int nwaves = gridDim.x * (blockDim.x >> 6);
    for (int base = wave * 64; base < n_edges; base += nwaves * 64) {
        const int cnt = min(64, n_edges - base);
        int s = 0, d = 0;
        float nrm = 0.0f;
        if (lane < cnt) {
            s = src[base + lane];
            d = dst[base + lane];
            nrm = dis[s] * dis[d];
        }
        for (int j = 0; j < cnt; j += EPI) {
            int jj = j + sub;
            int sj = __shfl(s, jj);
            int dj = __shfl(d, jj);
            float nj = __shfl(nrm, jj);
            if (jj < cnt) {
                float v = rows[(size_t)sj * C + ch] * nj;
                atomicAdd(&out[(size_t)dj * C + ch], v);
            }
        }
    }
}

// ---------------- finalize 1: h = relu(agg + xW*dis^2 + b1) ----------------
__global__ __launch_bounds__(256) void finalize1(float* __restrict__ agg,  // in-place -> h
                                                 const float* __restrict__ xW,
                                                 const float* __restrict__ dis,
                                                 const float* __restrict__ b1,
                                                 int n_nodes) {
    size_t i = (size_t)blockIdx.x * 256 + threadIdx.x;
    size_t total = (size_t)n_nodes * HIDC;
    if (i >= total) return;
    int n = (int)(i >> 6), c = (int)(i & 63);
    float d = dis[n];
    float v = agg[i] + xW[i] * d * d + b1[c];
    agg[i] = fmaxf(v, 0.0f);
}

// ---------------- finalize 2: split mu/logstd into d_out ----------------
__global__ __launch_bounds__(256) void finalize2(const float* __restrict__ agg2,
                                                 const float* __restrict__ hw,
                                                 const float* __restrict__ dis,
                                                 const float* __restrict__ bmu,
                                                 const float* __restrict__ bls,
                                                 float* __restrict__ out, int n_nodes) {
    size_t i = (size_t)blockIdx.x * 256 + threadIdx.x;
    size_t total = (size_t)n_nodes * 32;
    if (i >= total) return;
    int n = (int)(i >> 5), c = (int)(i & 31);
    float d = dis[n];
    float v = agg2[i] + hw[i] * d * d + (c < 16 ? bmu[c] : bls[c - 16]);
    if (c < 16)
        out[(size_t)n * 16 + c] = v;
    else
        out[(size_t)(n_nodes + n) * 16 + (c - 16)] = v;
}

extern "C" void kernel_launch(void* const* d_in, const int* in_sizes, int n_in,
                              void* d_out, int out_size, void* d_ws, size_t ws_size,
                              hipStream_t stream) {
    const float* x   = (const float*)d_in[0];
    const int*   ei  = (const int*)d_in[1];
    const float* W1  = (const float*)d_in[2];
    const float* b1  = (const float*)d_in[3];
    const float* Wmu = (const float*)d_in[4];
    const float* bmu = (const float*)d_in[5];
    const float* Wls = (const float*)d_in[6];
    const float* bls = (const float*)d_in[7];
    float* out = (float*)d_out;

    const int N = in_sizes[0] / INC;       // 100000
    const int E = in_sizes[1] / 2;         // 3200000
    const int* src = ei;
    const int* dst = ei + E;

    float* ws   = (float*)d_ws;
    float* dis  = ws;                         // N floats
    float* xW   = ws + 131072;                // N*64
    float* agg1 = xW + (size_t)N * HIDC;      // N*64, becomes h in-place
    float* hw   = xW;                         // N*32, reuses xW region
    float* agg2 = xW + (size_t)N * 32;        // N*32

    // degree -> dis
    init_deg<<<(N + 255) / 256, 256, 0, stream>>>(dis, N);
    count_deg<<<1024, 256, 0, stream>>>(dst, dis, E);
    finish_dis<<<(N + 255) / 256, 256, 0, stream>>>(dis, N);

    // conv1
    gemm_x_w<<<1024, 256, 0, stream>>>(x, W1, xW, N);
    hipMemsetAsync(agg1, 0, (size_t)N * HIDC * sizeof(float), stream);
    scatter_edges<HIDC><<<1024, 256, 0, stream>>>(xW, agg1, src, dst, dis, E);
    finalize1<<<(N * HIDC + 255) / 256, 256, 0, stream>>>(agg1, xW, dis, b1, N);

    // conv2 (mu and logstd fused: C=32)
    gemm_h_w<<<1024, 256, 0, stream>>>(agg1, Wmu, Wls, hw, N);
    hipMemsetAsync(agg2, 0, (size_t)N * 32 * sizeof(float), stream);
    scatter_edges<32><<<1024, 256, 0, stream>>>(hw, agg2, src, dst, dis, E);
    finalize2<<<(N * 32 + 255) / 256, 256, 0, stream>>>(agg2, hw, dis, bmu, bls, out, N);
}

// Round 2
// 951.309 us; speedup vs baseline: 1.5067x; 1.5067x over previous
//
#include <hip/hip_runtime.h>
#include <hip/hip_bf16.h>

#define HIDC 64
#define INC 128
#define OUTC 16

// ---------------- degree counting (int) ----------------
__global__ __launch_bounds__(256) void count_deg(const int* __restrict__ dst,
                                                 int* __restrict__ cnt, int n_edges) {
    int e = blockIdx.x * 256 + threadIdx.x;
    if (e < n_edges) atomicAdd(&cnt[dst[e]], 1);
}

__global__ __launch_bounds__(256) void finish_dis(const int* __restrict__ cnt,
                                                  float* __restrict__ dis, int n) {
    int i = blockIdx.x * 256 + threadIdx.x;
    if (i < n) dis[i] = rsqrtf((float)(cnt[i] + 1));  // +1 self-loop
}

// ---------------- exclusive scan over N counts (single block) ----------------
__global__ __launch_bounds__(1024) void scan_offsets(const int* __restrict__ cnt,
                                                     int* __restrict__ off, int n) {
    __shared__ int part[1024];
    const int chunk = (n + 1023) >> 10;
    const int begin = threadIdx.x * chunk;
    const int end = min(begin + chunk, n);
    int s = 0;
    for (int i = begin; i < end; ++i) s += cnt[i];
    part[threadIdx.x] = s;
    __syncthreads();
    for (int d = 1; d < 1024; d <<= 1) {
        int v = (threadIdx.x >= d) ? part[threadIdx.x - d] : 0;
        __syncthreads();
        part[threadIdx.x] += v;
        __syncthreads();
    }
    int prefix = (threadIdx.x == 0) ? 0 : part[threadIdx.x - 1];
    for (int i = begin; i < end; ++i) {
        off[i] = prefix;
        prefix += cnt[i];
    }
    if (end == n && begin < n) off[n] = prefix;
}

__global__ __launch_bounds__(256) void copy_off(const int* __restrict__ off,
                                                int* __restrict__ cur, int n) {
    int i = blockIdx.x * 256 + threadIdx.x;
    if (i < n) cur[i] = off[i];
}

// ---------------- CSR fill ----------------
__global__ __launch_bounds__(256) void fill_csr(const int* __restrict__ src,
                                                const int* __restrict__ dst,
                                                int* __restrict__ cur,
                                                int* __restrict__ csr, int n_edges) {
    int e = blockIdx.x * 256 + threadIdx.x;
    if (e < n_edges) {
        int slot = atomicAdd(&cur[dst[e]], 1);
        csr[slot] = src[e];
    }
}

// ---------------- GEMM 1: xW = x @ W1 ----------------
__global__ __launch_bounds__(256) void gemm_x_w(const float* __restrict__ x,
                                                const float* __restrict__ W,
                                                float* __restrict__ out, int n_nodes) {
    __shared__ float Wl[INC * HIDC];
    __shared__ float xr[4][INC];
    for (int i = threadIdx.x; i < INC * HIDC; i += 256) Wl[i] = W[i];
    const int wid = threadIdx.x >> 6, lane = threadIdx.x & 63;
    for (int base = blockIdx.x * 4; base < n_nodes; base += gridDim.x * 4) {
        int nrows = min(4, n_nodes - base);
        __syncthreads();
        for (int i = threadIdx.x; i < nrows * INC; i += 256)
            xr[i >> 7][i & 127] = x[(size_t)base * INC + i];
        __syncthreads();
        if (wid < nrows) {
            float acc = 0.f;
            #pragma unroll
            for (int k = 0; k < INC; ++k) acc += xr[wid][k] * Wl[k * HIDC + lane];
            out[(size_t)(base + wid) * HIDC + lane] = acc;
        }
    }
}

// ---------------- GEMM 2: hw = h @ [W_mu | W_ls] ----------------
__global__ __launch_bounds__(256) void gemm_h_w(const float* __restrict__ h,
                                                const float* __restrict__ Wmu,
                                                const float* __restrict__ Wls,
                                                float* __restrict__ out, int n_nodes) {
    __shared__ float Wl[HIDC * 32];
    __shared__ float hr[8][HIDC];
    for (int i = threadIdx.x; i < HIDC * OUTC; i += 256) {
        int k = i >> 4, c = i & 15;
        Wl[k * 32 + c]      = Wmu[i];
        Wl[k * 32 + 16 + c] = Wls[i];
    }
    const int wid = threadIdx.x >> 6, lane = threadIdx.x & 63;
    const int sub = lane >> 5, ch = lane & 31;
    for (int base = blockIdx.x * 8; base < n_nodes; base += gridDim.x * 8) {
        int nrows = min(8, n_nodes - base);
        __syncthreads();
        for (int i = threadIdx.x; i < nrows * HIDC; i += 256)
            hr[i >> 6][i & 63] = h[(size_t)base * HIDC + i];
        __syncthreads();
        int n = wid * 2 + sub;
        if (n < nrows) {
            float acc = 0.f;
            #pragma unroll
            for (int k = 0; k < HIDC; ++k) acc += hr[n][k] * Wl[k * 32 + ch];
            out[(size_t)(base + n) * 32 + ch] = acc;
        }
    }
}

// ---------------- gather conv1 (NOT in-place): h = relu(agg + self + b1) ----
__global__ __launch_bounds__(256) void gather64(const float* __restrict__ xW,
                                                float* __restrict__ h,
                                                const int* __restrict__ csr,
                                                const int* __restrict__ off,
                                                const float* __restrict__ dis,
                                                const float* __restrict__ b1,
                                                int n_nodes) {
    int wid = (blockIdx.x * 256 + threadIdx.x) >> 6;
    int lane = threadIdx.x & 63;
    if (wid >= n_nodes) return;
    const int node = wid;
    const int beg = off[node], end = off[node + 1];
    const float dn = dis[node];
    float acc = xW[(size_t)node * HIDC + lane] * dn * dn;
    int e = beg;
    for (; e + 4 <= end; e += 4) {
        int s0 = csr[e], s1 = csr[e + 1], s2 = csr[e + 2], s3 = csr[e + 3];
        float n0 = dis[s0] * dn, n1 = dis[s1] * dn, n2 = dis[s2] * dn, n3 = dis[s3] * dn;
        float r0 = xW[(size_t)s0 * HIDC + lane];
        float r1 = xW[(size_t)s1 * HIDC + lane];
        float r2 = xW[(size_t)s2 * HIDC + lane];
        float r3 = xW[(size_t)s3 * HIDC + lane];
        acc += r0 * n0 + r1 * n1 + r2 * n2 + r3 * n3;
    }
    for (; e < end; ++e) {
        int s = csr[e];
        acc += xW[(size_t)s * HIDC + lane] * dis[s] * dn;
    }
    h[(size_t)node * HIDC + lane] = fmaxf(acc + b1[lane], 0.0f);
}

// ---------------- gather conv2: write [mu | logstd] directly ----------------
__global__ __launch_bounds__(256) void gather32(const float* __restrict__ hw,
                                                const int* __restrict__ csr,
                                                const int* __restrict__ off,
                                                const float* __restrict__ dis,
                                                const float* __restrict__ bmu,
                                                const float* __restrict__ bls,
                                                float* __restrict__ out,
                                                int n_nodes) {
    int wid = (blockIdx.x * 256 + threadIdx.x) >> 6;
    int lane = threadIdx.x & 63;
    int half = lane >> 5, ch = lane & 31;
    int node = wid * 2 + half;
    if (node >= n_nodes) return;
    const int beg = off[node], end = off[node + 1];
    const float dn = dis[node];
    float acc = hw[(size_t)node * 32 + ch] * dn * dn;
    int e = beg;
    for (; e + 4 <= end; e += 4) {
        int s0 = csr[e], s1 = csr[e + 1], s2 = csr[e + 2], s3 = csr[e + 3];
        float n0 = dis[s0] * dn, n1 = dis[s1] * dn, n2 = dis[s2] * dn, n3 = dis[s3] * dn;
        float r0 = hw[(size_t)s0 * 32 + ch];
        float r1 = hw[(size_t)s1 * 32 + ch];
        float r2 = hw[(size_t)s2 * 32 + ch];
        float r3 = hw[(size_t)s3 * 32 + ch];
        acc += r0 * n0 + r1 * n1 + r2 * n2 + r3 * n3;
    }
    for (; e < end; ++e) {
        int s = csr[e];
        acc += hw[(size_t)s * 32 + ch] * dis[s] * dn;
    }
    float v = acc + (ch < 16 ? bmu[ch] : bls[ch - 16]);
    if (ch < 16)
        out[(size_t)node * 16 + ch] = v;
    else
        out[(size_t)(n_nodes + node) * 16 + (ch - 16)] = v;
}

extern "C" void kernel_launch(void* const* d_in, const int* in_sizes, int n_in,
                              void* d_out, int out_size, void* d_ws, size_t ws_size,
                              hipStream_t stream) {
    const float* x   = (const float*)d_in[0];
    const int*   ei  = (const int*)d_in[1];
    const float* W1  = (const float*)d_in[2];
    const float* b1  = (const float*)d_in[3];
    const float* Wmu = (const float*)d_in[4];
    const float* bmu = (const float*)d_in[5];
    const float* Wls = (const float*)d_in[6];
    const float* bls = (const float*)d_in[7];
    float* out = (float*)d_out;

    const int N = in_sizes[0] / INC;
    const int E = in_sizes[1] / 2;
    const int* src = ei;
    const int* dst = ei + E;

    // workspace layout (4-byte words):
    //   dis: [0, 131072)   cnt/cursor: [131072, 262144)   off: [262144, 393216)
    //   csr: [393216, 393216+E)   xW: next N*64   h: next N*64   (hw aliases xW)
    float* ws  = (float*)d_ws;
    float* dis = ws;
    int*   cnt = (int*)(ws + 131072);
    int*   off = (int*)(ws + 262144);
    int*   csr = (int*)(ws + 393216);
    float* xW  = ws + 393216 + (size_t)E;
    float* h   = xW + (size_t)N * HIDC;
    float* hw  = xW;  // xW dead once gather64 completes

    const int EB = (E + 255) / 256;
    const int NB = (N + 255) / 256;

    hipMemsetAsync(cnt, 0, (size_t)N * sizeof(int), stream);
    count_deg<<<EB, 256, 0, stream>>>(dst, cnt, E);
    finish_dis<<<NB, 256, 0, stream>>>(cnt, dis, N);

    scan_offsets<<<1, 1024, 0, stream>>>(cnt, off, N);
    copy_off<<<NB, 256, 0, stream>>>(off, cnt, N);
    fill_csr<<<EB, 256, 0, stream>>>(src, dst, cnt, csr, E);

    gemm_x_w<<<1024, 256, 0, stream>>>(x, W1, xW, N);
    gather64<<<(N * 64 + 255) / 256, 256, 0, stream>>>(xW, h, csr, off, dis, b1, N);

    gemm_h_w<<<1024, 256, 0, stream>>>(h, Wmu, Wls, hw, N);
    gather32<<<(((N + 1) / 2) * 64 + 255) / 256, 256, 0, stream>>>(hw, csr, off, dis, bmu, bls, out, N);
}

// Round 3
// 651.877 us; speedup vs baseline: 2.1988x; 1.4593x over previous
//
#include <hip/hip_runtime.h>
#include <hip/hip_bf16.h>

#define HIDC 64
#define INC 128
#define OUTC 16
#define SCAN_CHUNK 1024

// ---------------- degree counting ----------------
__global__ __launch_bounds__(256) void count_deg(const int* __restrict__ dst,
                                                 int* __restrict__ cnt, int n_edges) {
    int e = blockIdx.x * 256 + threadIdx.x;
    if (e < n_edges) atomicAdd(&cnt[dst[e]], 1);
}

__global__ __launch_bounds__(256) void finish_dis(const int* __restrict__ cnt,
                                                  float* __restrict__ dis, int n) {
    int i = blockIdx.x * 256 + threadIdx.x;
    if (i < n) dis[i] = rsqrtf((float)(cnt[i] + 1));  // +1 self-loop
}

// ---------------- hierarchical exclusive scan (3 kernels) ----------------
__global__ __launch_bounds__(256) void scan_k1(const int* __restrict__ cnt,
                                               int* __restrict__ partial, int n) {
    int base = blockIdx.x * SCAN_CHUNK;
    int lim = min(base + SCAN_CHUNK, n);
    int s = 0;
    for (int i = base + threadIdx.x; i < lim; i += 256) s += cnt[i];
    #pragma unroll
    for (int d = 32; d; d >>= 1) s += __shfl_down(s, d);
    __shared__ int wsum[4];
    if ((threadIdx.x & 63) == 0) wsum[threadIdx.x >> 6] = s;
    __syncthreads();
    if (threadIdx.x == 0) partial[blockIdx.x] = wsum[0] + wsum[1] + wsum[2] + wsum[3];
}

__global__ __launch_bounds__(256) void scan_k2(const int* __restrict__ partial,
                                               int* __restrict__ pbase,
                                               int* __restrict__ off, int nblk, int n) {
    __shared__ int sh[256];
    int v = (threadIdx.x < nblk) ? partial[threadIdx.x] : 0;
    sh[threadIdx.x] = v;
    __syncthreads();
    for (int d = 1; d < 256; d <<= 1) {
        int t = (threadIdx.x >= d) ? sh[threadIdx.x - d] : 0;
        __syncthreads();
        sh[threadIdx.x] += t;
        __syncthreads();
    }
    if (threadIdx.x < nblk) pbase[threadIdx.x] = sh[threadIdx.x] - v;  // exclusive
    if (threadIdx.x == nblk - 1) off[n] = sh[threadIdx.x];             // total = E
}

__global__ __launch_bounds__(256) void scan_k3(const int* __restrict__ cnt,
                                               const int* __restrict__ pbase,
                                               int* __restrict__ off,
                                               int* __restrict__ cur, int n) {
    int i0 = blockIdx.x * SCAN_CHUNK + threadIdx.x * 4;
    int c0 = 0, c1 = 0, c2 = 0, c3 = 0;
    if (i0 + 3 < n) {
        int4 t = *(const int4*)(cnt + i0);
        c0 = t.x; c1 = t.y; c2 = t.z; c3 = t.w;
    } else {
        if (i0 + 0 < n) c0 = cnt[i0 + 0];
        if (i0 + 1 < n) c1 = cnt[i0 + 1];
        if (i0 + 2 < n) c2 = cnt[i0 + 2];
        if (i0 + 3 < n) c3 = cnt[i0 + 3];
    }
    int tsum = c0 + c1 + c2 + c3;
    __shared__ int sh[256];
    sh[threadIdx.x] = tsum;
    __syncthreads();
    for (int d = 1; d < 256; d <<= 1) {
        int t = (threadIdx.x >= d) ? sh[threadIdx.x - d] : 0;
        __syncthreads();
        sh[threadIdx.x] += t;
        __syncthreads();
    }
    int pre = pbase[blockIdx.x] + sh[threadIdx.x] - tsum;
    int o0 = pre, o1 = pre + c0, o2 = o1 + c1, o3 = o2 + c2;
    if (i0 + 3 < n) {
        *(int4*)(off + i0) = make_int4(o0, o1, o2, o3);
        *(int4*)(cur + i0) = make_int4(o0, o1, o2, o3);
    } else {
        if (i0 + 0 < n) { off[i0 + 0] = o0; cur[i0 + 0] = o0; }
        if (i0 + 1 < n) { off[i0 + 1] = o1; cur[i0 + 1] = o1; }
        if (i0 + 2 < n) { off[i0 + 2] = o2; cur[i0 + 2] = o2; }
        if (i0 + 3 < n) { off[i0 + 3] = o3; cur[i0 + 3] = o3; }
    }
}

// ---------------- XCD-partitioned CSR fill ----------------
// blockIdx%8 selects a disjoint dst range (heuristically one XCD under
// round-robin dispatch -> each csr line written from a single L2).
// Correct for ANY block->XCD mapping: ranges are disjoint, every part
// grid-strides the full edge list.
__global__ __launch_bounds__(256) void fill_csr(const int* __restrict__ src,
                                                const int* __restrict__ dst,
                                                int* __restrict__ cur,
                                                int* __restrict__ csr,
                                                int n_edges, int nodes_per_part) {
    const int part = blockIdx.x & 7;
    const int lo = part * nodes_per_part;
    const int hi = lo + nodes_per_part;
    const int nblk = gridDim.x >> 3;
    const int bid = blockIdx.x >> 3;
    for (int e = bid * 256 + threadIdx.x; e < n_edges; e += nblk * 256) {
        int d = dst[e];
        if (d >= lo && d < hi) {
            int slot = atomicAdd(&cur[d], 1);
            csr[slot] = src[e];
        }
    }
}

// ---------------- GEMM 1: xW = x @ W1 ----------------
__global__ __launch_bounds__(256) void gemm_x_w(const float* __restrict__ x,
                                                const float* __restrict__ W,
                                                float* __restrict__ out, int n_nodes) {
    __shared__ float Wl[INC * HIDC];
    __shared__ float xr[4][INC];
    for (int i = threadIdx.x; i < INC * HIDC; i += 256) Wl[i] = W[i];
    const int wid = threadIdx.x >> 6, lane = threadIdx.x & 63;
    for (int base = blockIdx.x * 4; base < n_nodes; base += gridDim.x * 4) {
        int nrows = min(4, n_nodes - base);
        __syncthreads();
        for (int i = threadIdx.x; i < nrows * (INC / 4); i += 256)
            ((float4*)xr)[i] = ((const float4*)(x + (size_t)base * INC))[i];
        __syncthreads();
        if (wid < nrows) {
            float acc = 0.f;
            #pragma unroll
            for (int k = 0; k < INC; ++k) acc += xr[wid][k] * Wl[k * HIDC + lane];
            out[(size_t)(base + wid) * HIDC + lane] = acc;
        }
    }
}

// ---------------- GEMM 2: hw = h @ [W_mu | W_ls] ----------------
__global__ __launch_bounds__(256) void gemm_h_w(const float* __restrict__ h,
                                                const float* __restrict__ Wmu,
                                                const float* __restrict__ Wls,
                                                float* __restrict__ out, int n_nodes) {
    __shared__ float Wl[HIDC * 32];
    __shared__ float hr[8][HIDC];
    for (int i = threadIdx.x; i < HIDC * OUTC; i += 256) {
        int k = i >> 4, c = i & 15;
        Wl[k * 32 + c]      = Wmu[i];
        Wl[k * 32 + 16 + c] = Wls[i];
    }
    const int wid = threadIdx.x >> 6, lane = threadIdx.x & 63;
    const int sub = lane >> 5, ch = lane & 31;
    for (int base = blockIdx.x * 8; base < n_nodes; base += gridDim.x * 8) {
        int nrows = min(8, n_nodes - base);
        __syncthreads();
        for (int i = threadIdx.x; i < nrows * (HIDC / 4); i += 256)
            ((float4*)hr)[i] = ((const float4*)(h + (size_t)base * HIDC))[i];
        __syncthreads();
        int n = wid * 2 + sub;
        if (n < nrows) {
            float acc = 0.f;
            #pragma unroll
            for (int k = 0; k < HIDC; ++k) acc += hr[n][k] * Wl[k * 32 + ch];
            out[(size_t)(base + n) * 32 + ch] = acc;
        }
    }
}

// ---------------- gather conv1: float4, 4 edges in flight per wave ----------
__global__ __launch_bounds__(256) void gather64(const float4* __restrict__ xW4,
                                                float4* __restrict__ h4,
                                                const int* __restrict__ csr,
                                                const int* __restrict__ off,
                                                const float* __restrict__ dis,
                                                const float* __restrict__ b1,
                                                int n_nodes) {
    int node = (blockIdx.x * 256 + threadIdx.x) >> 6;
    int lane = threadIdx.x & 63;
    if (node >= n_nodes) return;
    const int beg = off[node], end = off[node + 1];
    const float dn = dis[node];
    const int sub = lane >> 4;   // which edge of the quad
    const int c4  = lane & 15;   // which float4 of the 64-ch row
    float4 acc = {0.f, 0.f, 0.f, 0.f};
    for (int base = beg; base < end; base += 64) {
        const int cnt = min(64, end - base);
        int s = 0; float nrm = 0.f;
        if (lane < cnt) { s = csr[base + lane]; nrm = dis[s] * dn; }
        for (int j = 0; j < cnt; j += 4) {
            int jj = j + sub;
            int sj = __shfl(s, jj);
            float nj = __shfl(nrm, jj);
            if (jj < cnt) {
                float4 r = xW4[(size_t)sj * 16 + c4];
                acc.x += r.x * nj; acc.y += r.y * nj;
                acc.z += r.z * nj; acc.w += r.w * nj;
            }
        }
    }
    // reduce across the 4 sub-groups (lane bits 4,5)
    acc.x += __shfl_xor(acc.x, 16); acc.y += __shfl_xor(acc.y, 16);
    acc.z += __shfl_xor(acc.z, 16); acc.w += __shfl_xor(acc.w, 16);
    acc.x += __shfl_xor(acc.x, 32); acc.y += __shfl_xor(acc.y, 32);
    acc.z += __shfl_xor(acc.z, 32); acc.w += __shfl_xor(acc.w, 32);
    if (sub == 0) {
        float4 self = xW4[(size_t)node * 16 + c4];
        float s2 = dn * dn;
        float4 b = ((const float4*)b1)[c4];
        float4 o;
        o.x = fmaxf(acc.x + self.x * s2 + b.x, 0.f);
        o.y = fmaxf(acc.y + self.y * s2 + b.y, 0.f);
        o.z = fmaxf(acc.z + self.z * s2 + b.z, 0.f);
        o.w = fmaxf(acc.w + self.w * s2 + b.w, 0.f);
        h4[(size_t)node * 16 + c4] = o;
    }
}

// ---------------- gather conv2: float4, 8 edges in flight per wave ----------
__global__ __launch_bounds__(256) void gather32(const float4* __restrict__ hw4,
                                                const int* __restrict__ csr,
                                                const int* __restrict__ off,
                                                const float* __restrict__ dis,
                                                const float* __restrict__ bmu,
                                                const float* __restrict__ bls,
                                                float* __restrict__ out,
                                                int n_nodes) {
    int node = (blockIdx.x * 256 + threadIdx.x) >> 6;
    int lane = threadIdx.x & 63;
    if (node >= n_nodes) return;
    const int beg = off[node], end = off[node + 1];
    const float dn = dis[node];
    const int sub = lane >> 3;   // which edge of the oct
    const int c4  = lane & 7;    // which float4 of the 32-ch row
    float4 acc = {0.f, 0.f, 0.f, 0.f};
    for (int base = beg; base < end; base += 64) {
        const int cnt = min(64, end - base);
        int s = 0; float nrm = 0.f;
        if (lane < cnt) { s = csr[base + lane]; nrm = dis[s] * dn; }
        for (int j = 0; j < cnt; j += 8) {
            int jj = j + sub;
            int sj = __shfl(s, jj);
            float nj = __shfl(nrm, jj);
            if (jj < cnt) {
                float4 r = hw4[(size_t)sj * 8 + c4];
                acc.x += r.x * nj; acc.y += r.y * nj;
                acc.z += r.z * nj; acc.w += r.w * nj;
            }
        }
    }
    acc.x += __shfl_xor(acc.x, 8);  acc.y += __shfl_xor(acc.y, 8);
    acc.z += __shfl_xor(acc.z, 8);  acc.w += __shfl_xor(acc.w, 8);
    acc.x += __shfl_xor(acc.x, 16); acc.y += __shfl_xor(acc.y, 16);
    acc.z += __shfl_xor(acc.z, 16); acc.w += __shfl_xor(acc.w, 16);
    acc.x += __shfl_xor(acc.x, 32); acc.y += __shfl_xor(acc.y, 32);
    acc.z += __shfl_xor(acc.z, 32); acc.w += __shfl_xor(acc.w, 32);
    if (sub == 0) {
        float4 self = hw4[(size_t)node * 8 + c4];
        float s2 = dn * dn;
        float4 b = (c4 < 4) ? ((const float4*)bmu)[c4] : ((const float4*)bls)[c4 - 4];
        float4 o;
        o.x = acc.x + self.x * s2 + b.x;
        o.y = acc.y + self.y * s2 + b.y;
        o.z = acc.z + self.z * s2 + b.z;
        o.w = acc.w + self.w * s2 + b.w;
        if (c4 < 4)
            ((float4*)out)[(size_t)node * 4 + c4] = o;
        else
            ((float4*)out)[((size_t)n_nodes + node) * 4 + (c4 - 4)] = o;
    }
}

extern "C" void kernel_launch(void* const* d_in, const int* in_sizes, int n_in,
                              void* d_out, int out_size, void* d_ws, size_t ws_size,
                              hipStream_t stream) {
    const float* x   = (const float*)d_in[0];
    const int*   ei  = (const int*)d_in[1];
    const float* W1  = (const float*)d_in[2];
    const float* b1  = (const float*)d_in[3];
    const float* Wmu = (const float*)d_in[4];
    const float* bmu = (const float*)d_in[5];
    const float* Wls = (const float*)d_in[6];
    const float* bls = (const float*)d_in[7];
    float* out = (float*)d_out;

    const int N = in_sizes[0] / INC;
    const int E = in_sizes[1] / 2;
    const int* src = ei;
    const int* dst = ei + E;

    // workspace (4-byte words):
    //   dis [0,131072) | cnt/cursor [131072,262144) | off [262144,393216)
    //   csr [393216, 393216+E) | xW next N*64 | h next N*64 ; hw aliases xW
    //   scan partials live in the cnt region's tail (beyond N)
    float* ws  = (float*)d_ws;
    float* dis = ws;
    int*   cnt = (int*)(ws + 131072);            // doubles as cursor
    int*   off = (int*)(ws + 262144);
    int*   csr = (int*)(ws + 393216);
    float* xW  = ws + 393216 + (size_t)E;
    float* h   = xW + (size_t)N * HIDC;
    float* hw  = xW;                              // xW dead after gather64
    int*   partial = cnt + 100352;                // 256 ints spare (N<=100000)
    int*   pbase   = cnt + 100608;

    const int EB = (E + 255) / 256;
    const int NB = (N + 255) / 256;
    const int SB = (N + SCAN_CHUNK - 1) / SCAN_CHUNK;  // <=256

    hipMemsetAsync(cnt, 0, (size_t)N * sizeof(int), stream);
    count_deg<<<EB, 256, 0, stream>>>(dst, cnt, E);
    finish_dis<<<NB, 256, 0, stream>>>(cnt, dis, N);

    scan_k1<<<SB, 256, 0, stream>>>(cnt, partial, N);
    scan_k2<<<1, 256, 0, stream>>>(partial, pbase, off, SB, N);
    scan_k3<<<SB, 256, 0, stream>>>(cnt, pbase, off, cnt /*cursor*/, N);

    fill_csr<<<1024, 256, 0, stream>>>(src, dst, cnt, csr, E, (N + 7) / 8);

    gemm_x_w<<<1024, 256, 0, stream>>>(x, W1, xW, N);
    gather64<<<(N * 64 + 255) / 256, 256, 0, stream>>>((const float4*)xW, (float4*)h,
                                                       csr, off, dis, b1, N);

    gemm_h_w<<<1024, 256, 0, stream>>>(h, Wmu, Wls, hw, N);
    gather32<<<(N * 64 + 255) / 256, 256, 0, stream>>>((const float4*)hw, csr, off, dis,
                                                       bmu, bls, out, N);
}